// Round 3
// baseline (649.141 us; speedup 1.0000x reference)
//
#include <hip/hip_runtime.h>
#include <hip/hip_bf16.h>
#include <math.h>

// N = 100000, E = 3.2M, F_in = 128, H = C = 16 (derived from in_sizes at launch).
// Harness delivers integer inputs as int32.
//
// Norm factorization: u = dinv .* (h @ W); out[d] = dinv[d]*(sum_{s->d} u[s] + u[d]) + b.
// Atomic chain lengths (avg deg 32) are attacked with replicated accumulators:
//   deg: RD replicas, agg: RS replicas, merged in the consumer kernels.

#define F_IN 128
#define H 16

// --- degree histogram into RD replicas ---
__global__ void deg_rep_kernel(const int* __restrict__ dst, float* __restrict__ degrep,
                               int E, int N, int RDm1) {
    int e = blockIdx.x * blockDim.x + threadIdx.x;
    if (e < E) {
        int r = e & RDm1;
        atomicAdd(&degrep[(size_t)r * N + dst[e]], 1.0f);
    }
}

// dinv[i] = rsqrt(1 + sum_r degrep[r][i])   (the +1 is the self-loop)
__global__ void dinv_kernel(const float* __restrict__ degrep, float* __restrict__ dinv,
                            int N, int RD) {
    int i = blockIdx.x * blockDim.x + threadIdx.x;
    if (i < N) {
        float s = 1.0f;
        for (int r = 0; r < RD; r++) s += degrep[(size_t)r * N + i];
        dinv[i] = rsqrtf(s);
    }
}

// u[i][j] = dinv[i] * sum_k x[i][k] * W1[k][j]
// block = 256 threads = 16 rows x 16 cols. x tile staged via LDS (coalesced float4),
// row pad +4 floats to break 4-way bank conflicts on the broadcast read.
#define XPAD 132
__global__ void xw1_kernel(const float* __restrict__ x, const float* __restrict__ W1,
                           const float* __restrict__ dinv, float* __restrict__ u, int n) {
    __shared__ float sW1[F_IN * H];
    __shared__ float sx[16 * XPAD];
    for (int t = threadIdx.x; t < F_IN * H; t += blockDim.x) sW1[t] = W1[t];

    int base = blockIdx.x * 16;
    // stage 16 rows x 128 floats = 512 float4; 2 per thread
    for (int idx = threadIdx.x; idx < 512; idx += 256) {
        int r = idx >> 5;            // 0..15
        int kk = (idx & 31) << 2;    // 0,4,...,124
        int row = base + r;
        float4 v = make_float4(0.f, 0.f, 0.f, 0.f);
        if (row < n) v = *(const float4*)(x + (size_t)row * F_IN + kk);
        *(float4*)(sx + r * XPAD + kk) = v;
    }
    __syncthreads();

    int r = threadIdx.x >> 4;
    int j = threadIdx.x & 15;
    int row = base + r;
    if (row >= n) return;

    const float* xr = sx + r * XPAD;
    float acc = 0.0f;
#pragma unroll 16
    for (int k = 0; k < F_IN; k++) acc += xr[k] * sW1[k * H + j];
    u[(size_t)row * H + j] = dinv[row] * acc;
}

// one (edge, channel) per thread: aggrep[r][dst][j] += u[src][j]
__global__ void scatter_rep_kernel(const int* __restrict__ src, const int* __restrict__ dst,
                                   const float* __restrict__ u, float* __restrict__ aggrep,
                                   int E, int N, int RSm1) {
    int t = blockIdx.x * blockDim.x + threadIdx.x;
    int e = t >> 4;
    int j = t & 15;
    if (e < E) {
        int s = src[e];
        int d = dst[e];
        int r = (e >> 2) & RSm1;   // whole wave (4 edges) shares a replica
        atomicAdd(&aggrep[((size_t)r * N + d) * H + j], u[(size_t)s * H + j]);
    }
}

// h1 = relu(dinv*(sum_r agg + u) + b1); u2 = dinv*(h1 @ W2) overwrites u.
__global__ void finalize1_kernel(const float* __restrict__ aggrep, float* __restrict__ u,
                                 const float* __restrict__ dinv, const float* __restrict__ b1,
                                 const float* __restrict__ W2, int n, int N, int RS) {
    __shared__ float sW2[H * H];
    __shared__ float sb1[H];
    if (threadIdx.x < H * H) sW2[threadIdx.x] = W2[threadIdx.x];
    if (threadIdx.x < H) sb1[threadIdx.x] = b1[threadIdx.x];
    __syncthreads();

    int row = blockIdx.x * 16 + (threadIdx.x >> 4);
    int j = threadIdx.x & 15;
    if (row >= n) return;

    float a = u[(size_t)row * H + j];
    for (int r = 0; r < RS; r++) a += aggrep[((size_t)r * N + row) * H + j];

    float di = dinv[row];
    float h = di * a + sb1[j];
    h = fmaxf(h, 0.0f);

    float acc = 0.0f;
#pragma unroll
    for (int k = 0; k < H; k++) {
        float hk = __shfl(h, k, 16);
        acc += hk * sW2[k * H + j];
    }
    u[(size_t)row * H + j] = di * acc;
}

// v = dinv*(sum_r agg + u) + b2; out = log_softmax(v) over 16.
__global__ void finalize2_kernel(const float* __restrict__ aggrep, const float* __restrict__ u,
                                 const float* __restrict__ dinv, const float* __restrict__ b2,
                                 float* __restrict__ out, int n, int N, int RS) {
    __shared__ float sb2[H];
    if (threadIdx.x < H) sb2[threadIdx.x] = b2[threadIdx.x];
    __syncthreads();

    int row = blockIdx.x * 16 + (threadIdx.x >> 4);
    int j = threadIdx.x & 15;
    if (row >= n) return;

    float a = u[(size_t)row * H + j];
    for (int r = 0; r < RS; r++) a += aggrep[((size_t)r * N + row) * H + j];

    float di = dinv[row];
    float v = di * a + sb2[j];

    float m = v;
#pragma unroll
    for (int off = 8; off >= 1; off >>= 1) m = fmaxf(m, __shfl_xor(m, off, 16));
    float ex = __expf(v - m);
    float s = ex;
#pragma unroll
    for (int off = 8; off >= 1; off >>= 1) s += __shfl_xor(s, off, 16);

    out[(size_t)row * H + j] = v - m - __logf(s);
}

extern "C" void kernel_launch(void* const* d_in, const int* in_sizes, int n_in,
                              void* d_out, int out_size, void* d_ws, size_t ws_size,
                              hipStream_t stream) {
    const float* x = (const float*)d_in[0];
    const int* edge_index = (const int*)d_in[1];
    const float* W1 = (const float*)d_in[2];
    const float* b1 = (const float*)d_in[3];
    const float* W2 = (const float*)d_in[4];
    const float* b2 = (const float*)d_in[5];
    float* out = (float*)d_out;

    const int N = in_sizes[0] / F_IN;
    const int E = in_sizes[1] / 2;
    const int* src = edge_index;
    const int* dst = edge_index + E;

    // Replica counts, degraded if workspace is tight.
    size_t avail_floats = ws_size / sizeof(float);
    int RS = 4, RD = 8;
    while ((size_t)N * (1 + 16 + (size_t)16 * RS + RD) > avail_floats && RS > 1) RS >>= 1;
    while ((size_t)N * (1 + 16 + (size_t)16 * RS + RD) > avail_floats && RD > 1) RD >>= 1;

    // ws layout (floats): dinv[N] | u[16N] | aggrep[RS*16N] | degrep[RD*N]
    float* dinv   = (float*)d_ws;
    float* u      = dinv + N;
    float* aggrep = u + (size_t)N * H;
    float* degrep = aggrep + (size_t)RS * N * H;

    // --- degree / dinv ---
    hipMemsetAsync(degrep, 0, (size_t)RD * N * sizeof(float), stream);
    hipMemsetAsync(aggrep, 0, (size_t)RS * N * H * sizeof(float), stream);
    deg_rep_kernel<<<(E + 255) / 256, 256, 0, stream>>>(dst, degrep, E, N, RD - 1);
    dinv_kernel<<<(N + 255) / 256, 256, 0, stream>>>(degrep, dinv, N, RD);

    // --- layer 1 ---
    xw1_kernel<<<(N + 15) / 16, 256, 0, stream>>>(x, W1, dinv, u, N);
    {
        long long tot = (long long)E * H;
        scatter_rep_kernel<<<(int)((tot + 255) / 256), 256, 0, stream>>>(src, dst, u, aggrep, E, N, RS - 1);
    }
    finalize1_kernel<<<(N + 15) / 16, 256, 0, stream>>>(aggrep, u, dinv, b1, W2, N, N, RS);

    // --- layer 2 ---
    hipMemsetAsync(aggrep, 0, (size_t)RS * N * H * sizeof(float), stream);
    {
        long long tot = (long long)E * H;
        scatter_rep_kernel<<<(int)((tot + 255) / 256), 256, 0, stream>>>(src, dst, u, aggrep, E, N, RS - 1);
    }
    finalize2_kernel<<<(N + 15) / 16, 256, 0, stream>>>(aggrep, u, dinv, b2, out, N, N, RS);
}